// Round 5
// baseline (1614.505 us; speedup 1.0000x reference)
//
#include <hip/hip_runtime.h>
#include <math.h>

#define BB 32
#define TT 720
#define NNN 321
#define KK 25
#define PP 12
#define TCH 24   // T-chunk per thread in mavg; 720 = 30 * 24

constexpr int L0 = BB * TT * NNN;          // 7,395,840
constexpr int L1 = (L0 + 15) / 2;          // 3,697,927
constexpr int L2 = (L1 + 15) / 2;          // 1,848,971
constexpr int L3 = (L2 + 15) / 2;          // 924,493
constexpr unsigned KMED = (unsigned)((L1 - 1) / 2 + 1);
constexpr float AA = 0.85f;

// dwt23 tile params
#define NC3 1024
constexpr int LEN2T = 2 * NC3 + 32;
constexpr int LEN1T = 4 * NC3 + 80;
constexpr int GD23 = (L3 + NC3 - 1) / NC3;   // 903 blocks per signal
// dwt1 params
#define DW1P 1024                            // pairs per block (2048 outputs/signal)
constexpr int GD1 = (L1 / 2 + DW1P) / DW1P;  // 1806
// compact params
#define NCB 256                              // compact blocks per signal
// idwt tile params
#define NF0 4096
constexpr int N1T = NF0 / 2 + 8;             // 2056
constexpr int N2T = N1T / 2 + 7;             // 1035
constexpr int NQ3 = (N2T + 1) / 2;           // 518

// 16-tap analysis low-pass (from reference)
constexpr float DLO[16] = {
    -0.0033824159510061256f, -0.0005421323317911481f, 0.03169508781149298f,
    0.007607487324917605f,  -0.1432942383508097f,    -0.061273359067658524f,
    0.4813596512583722f,     0.7771857517005235f,     0.36444189483533895f,
    -0.05194583810770904f,  -0.027219029917056003f,   0.049137179673607506f,
    0.003808752013890615f,  -0.01495225833704823f,   -0.0003029205147213668f,
    0.0018899503327594609f };

// ---------------- init: zero histogram state ----------------
// hist0: 2048 bins/signal, line-spread stride 4 words -> 16384 u32
// hist1: 4096 bins/signal dense -> 8192 u32 ; cnt: 2
__global__ void init_kernel(unsigned* __restrict__ hist0,
                            unsigned* __restrict__ hist1,
                            unsigned* __restrict__ cnt) {
    int g = blockIdx.x * blockDim.x + threadIdx.x;
    if (g < 16384) hist0[g] = 0;
    if (g < 8192)  hist1[g] = 0;
    if (g < 2)     cnt[g] = 0;
}

// ---------------- moving average + residual (running sum along T) ----------------
__global__ void mavg_kernel(const float* __restrict__ x,
                            float* __restrict__ trend,
                            float* __restrict__ res) {
    constexpr int NCH = TT / TCH;
    int gid = blockIdx.x * blockDim.x + threadIdx.x;
    if (gid >= BB * NCH * NNN) return;
    int n    = gid % NNN;
    int rest = gid / NNN;
    int ch   = rest % NCH;
    int b    = rest / NCH;
    int t0   = ch * TCH;
    const float* xb = x + (size_t)b * TT * NNN + n;
    float sum = 0.f;
#pragma unroll
    for (int dt = -PP; dt <= PP; ++dt) {
        int tt = t0 + dt;
        tt = tt < 0 ? 0 : (tt >= TT ? TT - 1 : tt);
        sum += xb[(size_t)tt * NNN];
    }
    size_t base = (size_t)b * TT * NNN + (size_t)t0 * NNN + n;
    for (int i = 0; i < TCH; ++i) {
        int t = t0 + i;
        float tr = sum * (1.0f / (float)KK);
        size_t idx = base + (size_t)i * NNN;
        trend[idx] = tr;
        res[idx] = xb[(size_t)t * NNN] - tr;
        int tp = t + 1 + PP; if (tp > TT - 1) tp = TT - 1;
        int tm = t - PP;     if (tm < 0)      tm = 0;
        sum += xb[(size_t)tp * NNN] - xb[(size_t)tm * NNN];
    }
}

// ---------------- DWT level 1 + fused 11-bit histogram of |cd1| ----------------
__global__ void dwt1_hist(const float* __restrict__ trend, const float* __restrict__ res,
                          float* __restrict__ ca1, float* __restrict__ cd1,
                          unsigned* __restrict__ hist0) {
    __shared__ unsigned sh[4096];   // 2 signals x 2048 bins (bits[30:20], sign=0)
    for (int i = threadIdx.x; i < 4096; i += 256) sh[i] = 0;
    __syncthreads();
    int P0 = blockIdx.x * DW1P;
    for (int j = threadIdx.x; j < DW1P; j += 256) {
        int o = (P0 + j) * 2;
        if (o >= L1) break;
#pragma unroll
        for (int s = 0; s < 2; ++s) {
            const float* a = s ? res : trend;
            float* pca = ca1 + (size_t)s * L1;
            float* pcd = cd1 + (size_t)s * L1;
            if (2 * o - 14 >= 0 && 2 * o + 3 < L0 && o + 1 < L1) {
                const float* p = a + 2 * o - 14;
                float v[18];
#pragma unroll
                for (int k = 0; k < 18; ++k) v[k] = p[k];
                float slo0 = 0.f, shi0 = 0.f, slo1 = 0.f, shi1 = 0.f;
#pragma unroll
                for (int k = 0; k < 16; ++k) {
                    float h = (k & 1) ? DLO[15 - k] : -DLO[15 - k];
                    slo0 = fmaf(DLO[k], v[15 - k], slo0);
                    shi0 = fmaf(h,      v[15 - k], shi0);
                    slo1 = fmaf(DLO[k], v[17 - k], slo1);
                    shi1 = fmaf(h,      v[17 - k], shi1);
                }
                float2 c2; c2.x = slo0; c2.y = slo1;
                float2 d2; d2.x = shi0; d2.y = shi1;
                *(float2*)(pca + o) = c2;
                *(float2*)(pcd + o) = d2;
                atomicAdd(&sh[(s << 11) | (__float_as_uint(fabsf(shi0)) >> 20)], 1u);
                atomicAdd(&sh[(s << 11) | (__float_as_uint(fabsf(shi1)) >> 20)], 1u);
            } else {
                int oend = (o + 2 < L1) ? o + 2 : L1;
                for (int o2 = o; o2 < oend; ++o2) {
                    float slo = 0.f, shi = 0.f;
                    int bidx = 2 * o2 + 1;
#pragma unroll
                    for (int k = 0; k < 16; ++k) {
                        int idx = bidx - k;
                        if (idx < 0) idx = -1 - idx;
                        if (idx >= L0) idx = 2 * L0 - 1 - idx;
                        float vv = a[idx];
                        slo = fmaf(DLO[k], vv, slo);
                        float h = (k & 1) ? DLO[15 - k] : -DLO[15 - k];
                        shi = fmaf(h, vv, shi);
                    }
                    pca[o2] = slo; pcd[o2] = shi;
                    atomicAdd(&sh[(s << 11) | (__float_as_uint(fabsf(shi)) >> 20)], 1u);
                }
            }
        }
    }
    __syncthreads();
    for (int i = threadIdx.x; i < 4096; i += 256) {
        unsigned c = sh[i];
        if (c) atomicAdd(&hist0[i << 2], c);   // stride-4 words: spread lines
    }
}

// ---------------- merged: dwt23 tiles + median candidate compaction ----------------
__global__ void dwt23_compact(const float* __restrict__ ca1,
                              float* __restrict__ cd2,
                              float* __restrict__ ca3,
                              float* __restrict__ cd3,
                              const float* __restrict__ cd1,
                              const unsigned* __restrict__ hist0,
                              unsigned* __restrict__ hist1,
                              unsigned* __restrict__ cand,
                              unsigned* __restrict__ cnt) {
    __shared__ float smem[LEN1T + LEN2T];       // union: dwt23 tiles / compact hist
    __shared__ unsigned wsum[4];
    __shared__ unsigned sdig;
    int db = blockIdx.x;
    if (db < 2 * GD23) {
        // ---- dwt23 part (identical math to R4) ----
        int s = db & 1;
        int C0 = (db >> 1) * NC3;
        float* s1 = smem;
        float* s2 = smem + LEN1T;
        const float* a1 = ca1 + (size_t)s * L1;
        int T0 = 2 * C0 - 14;
        int S1 = 4 * C0 - 42; if (S1 < 0) S1 = 0;
        int E1 = 2 * (T0 + LEN2T) + 2; if (E1 > L1) E1 = L1;
        int len1 = E1 - S1;
        for (int i = threadIdx.x; i < len1; i += 256) s1[i] = a1[S1 + i];
        __syncthreads();
        float* pcd2 = cd2 + (size_t)s * L2;
        for (int i = threadIdx.x; i < LEN2T; i += 256) {
            int e = T0 + i;
            if (e < 0 || e >= L2) continue;
            int base = 2 * e + 1;
            float slo = 0.f, shi = 0.f;
#pragma unroll
            for (int j = 0; j < 16; ++j) {
                int idx = base - j;
                if (idx < 0) idx = -1 - idx;
                if (idx >= L1) idx = 2 * L1 - 1 - idx;
                float v = s1[idx - S1];
                slo = fmaf(DLO[j], v, slo);
                float h = (j & 1) ? DLO[15 - j] : -DLO[15 - j];
                shi = fmaf(h, v, shi);
            }
            s2[i] = slo;
            if (e >= 2 * C0 && e < 2 * C0 + 2 * NC3) pcd2[e] = shi;
        }
        __syncthreads();
        for (int i = threadIdx.x; i < LEN2T; i += 256) {
            int e = T0 + i;
            if (e < 0)        s2[i] = s2[(-1 - e) - T0];
            else if (e >= L2) s2[i] = s2[(2 * L2 - 1 - e) - T0];
        }
        __syncthreads();
        float* pca3 = ca3 + (size_t)s * L3;
        float* pcd3 = cd3 + (size_t)s * L3;
        for (int i = threadIdx.x; i < NC3; i += 256) {
            int o = C0 + i;
            if (o >= L3) break;
            int b2 = 2 * o + 1 - T0;
            float slo = 0.f, shi = 0.f;
#pragma unroll
            for (int j = 0; j < 16; ++j) {
                float v = s2[b2 - j];
                slo = fmaf(DLO[j], v, slo);
                float h = (j & 1) ? DLO[15 - j] : -DLO[15 - j];
                shi = fmaf(h, v, shi);
            }
            pca3[o] = slo;
            pcd3[o] = shi;
        }
    } else {
        // ---- compact part: find median's 11-bit bucket, compact + hist next 12 bits ----
        int cb = db - 2 * GD23;
        int s = cb >> 8;            // NCB = 256 blocks per signal
        int bx = cb & 255;
        int t = threadIdx.x;
        unsigned* shh = (unsigned*)smem;   // 4096 bins
        for (int i = t; i < 4096; i += 256) shh[i] = 0;
        // scan hist0 of this signal: 2048 bins, chunk 8 per thread
        unsigned loc[8]; unsigned csum = 0;
#pragma unroll
        for (int j = 0; j < 8; ++j) { loc[j] = hist0[((s << 11) + t * 8 + j) << 2]; csum += loc[j]; }
        unsigned v = csum;
        int lane = t & 63, wv = t >> 6;
#pragma unroll
        for (int off = 1; off < 64; off <<= 1) {
            unsigned u = (unsigned)__shfl_up((int)v, off, 64);
            if (lane >= off) v += u;
        }
        if (lane == 63) wsum[wv] = v;
        __syncthreads();
        unsigned base = 0;
        for (int w2 = 0; w2 < wv; ++w2) base += wsum[w2];
        unsigned incl = base + v, excl = incl - csum;
        if (excl < KMED && incl >= KMED) {
            unsigned run = excl;
            for (int j = 0; j < 8; ++j) {
                if (run + loc[j] >= KMED) { sdig = (unsigned)(t * 8 + j); break; }
                run += loc[j];
            }
        }
        __syncthreads();
        unsigned d0 = sdig;
        // stream cd1[s], compact matches, LDS-hist bits[19:8]
        const float* ds = cd1 + (size_t)s * L1;
        for (int i = bx * 256 + t; i < L1; i += NCB * 256) {
            unsigned u = __float_as_uint(fabsf(ds[i]));
            if ((u >> 20) == d0) {
                unsigned pos = atomicAdd(&cnt[s], 1u);
                cand[(size_t)s * L1 + pos] = u;
                atomicAdd(&shh[(u >> 8) & 0xFFFu], 1u);
            }
        }
        __syncthreads();
        for (int i = t; i < 4096; i += 256) {
            unsigned c = shh[i];
            if (c) atomicAdd(&hist1[(s << 12) + i], c);
        }
    }
}

// ---------------- final select: finish 20-bit select over candidates, compute lambda ----
__global__ void select_final(const unsigned* __restrict__ hist0,
                             const unsigned* __restrict__ hist1,
                             const unsigned* __restrict__ cand,
                             const unsigned* __restrict__ cnt,
                             float* __restrict__ lamArr) {
    int s = blockIdx.x;
    int t = threadIdx.x;
    __shared__ unsigned shf[256];
    __shared__ unsigned wsum[4];
    __shared__ unsigned sd0, sk1, sd1, sk2;
    int lane = t & 63, wv = t >> 6;
    // phase A: digit0 over 2048 strided bins (threads < 256)
    if (t < 256) {
        unsigned loc[8]; unsigned csum = 0;
#pragma unroll
        for (int j = 0; j < 8; ++j) { loc[j] = hist0[((s << 11) + t * 8 + j) << 2]; csum += loc[j]; }
        unsigned v = csum;
#pragma unroll
        for (int off = 1; off < 64; off <<= 1) {
            unsigned u = (unsigned)__shfl_up((int)v, off, 64);
            if (lane >= off) v += u;
        }
        if (lane == 63) wsum[wv] = v;
        __syncthreads();
        unsigned base = 0;
        for (int w2 = 0; w2 < wv; ++w2) base += wsum[w2];
        unsigned incl = base + v, excl = incl - csum;
        if (excl < KMED && incl >= KMED) {
            unsigned run = excl;
            for (int j = 0; j < 8; ++j) {
                if (run + loc[j] >= KMED) { sd0 = (unsigned)(t * 8 + j); sk1 = KMED - run; break; }
                run += loc[j];
            }
        }
    } else { __syncthreads(); }
    __syncthreads();
    unsigned k1 = sk1, d0 = sd0;
    // phase B: digit1 over 4096 dense bins (threads < 256)
    if (t < 256) {
        unsigned loc[16]; unsigned csum = 0;
#pragma unroll
        for (int j = 0; j < 16; ++j) { loc[j] = hist1[(s << 12) + t * 16 + j]; csum += loc[j]; }
        unsigned v = csum;
#pragma unroll
        for (int off = 1; off < 64; off <<= 1) {
            unsigned u = (unsigned)__shfl_up((int)v, off, 64);
            if (lane >= off) v += u;
        }
        if (lane == 63) wsum[wv] = v;
        __syncthreads();
        unsigned base = 0;
        for (int w2 = 0; w2 < wv; ++w2) base += wsum[w2];
        unsigned incl = base + v, excl = incl - csum;
        if (excl < k1 && incl >= k1) {
            unsigned run = excl;
            for (int j = 0; j < 16; ++j) {
                if (run + loc[j] >= k1) { sd1 = (unsigned)(t * 16 + j); sk2 = k1 - run; break; }
                run += loc[j];
            }
        }
    } else { __syncthreads(); }
    __syncthreads();
    unsigned d1 = sd1, k2 = sk2;
    // phase C: hist last 8 bits over matching candidates (all threads)
    if (t < 256) shf[t] = 0;
    __syncthreads();
    unsigned n = cnt[s];
    unsigned pref24 = (d0 << 12) | d1;
    const unsigned* cs = cand + (size_t)s * L1;
    for (unsigned i = t; i < n; i += blockDim.x) {
        unsigned u = cs[i];
        if ((u >> 8) == pref24) atomicAdd(&shf[u & 0xFFu], 1u);
    }
    __syncthreads();
    // phase D: digit2 over 256 bins, single wave
    if (t < 64) {
        unsigned loc[4]; unsigned csum = 0;
#pragma unroll
        for (int j = 0; j < 4; ++j) { loc[j] = shf[t * 4 + j]; csum += loc[j]; }
        unsigned v = csum;
#pragma unroll
        for (int off = 1; off < 64; off <<= 1) {
            unsigned u = (unsigned)__shfl_up((int)v, off, 64);
            if (lane >= off) v += u;
        }
        unsigned incl = v, excl = v - csum;
        if (excl < k2 && incl >= k2) {
            unsigned run = excl;
            for (int j = 0; j < 4; ++j) {
                if (run + loc[j] >= k2) {
                    unsigned med = (d0 << 20) | (d1 << 8) | (unsigned)(t * 4 + j);
                    float m = __uint_as_float(med);
                    lamArr[s] = (m / 0.6745f) * sqrtf(2.0f * logf((float)L0));
                    break;
                }
                run += loc[j];
            }
        }
    }
}

// ---------------- soft threshold ----------------
__device__ __forceinline__ float sthr(float d, float lam, float alam) {
    float ad = fabsf(d);
    return (ad >= lam) ? copysignf(ad - alam, d) : 0.f;
}

// ---------------- fused 3-level IDWT, fully LDS-staged ----------------
__global__ void idwt_fused(const float* __restrict__ ca3,
                           const float* __restrict__ cd3,
                           const float* __restrict__ cd2,
                           const float* __restrict__ cd1,
                           const float* __restrict__ trend,
                           const float* __restrict__ res,
                           float* __restrict__ out,
                           const float* __restrict__ lamArr) {
    int s = blockIdx.y;
    int F0 = blockIdx.x * NF0;
    float lam = lamArr[s], alam = AA * lam;
    const float* pa3 = ca3 + (size_t)s * L3;
    const float* pd3 = cd3 + (size_t)s * L3;
    const float* pd2 = cd2 + (size_t)s * L2;
    const float* pd1 = cd1 + (size_t)s * L1;
    __shared__ float r2[N2T + 1];
    __shared__ float r1[N1T];
    __shared__ float t1[N1T];        // thresholded cd1 tile
    __shared__ float t2[N2T + 1];    // thresholded cd2 tile
    __shared__ float t3a[NQ3 + 8];   // ca3 tile
    __shared__ float t3d[NQ3 + 8];   // thresholded cd3 tile
    int A1 = F0 >> 1, A2 = F0 >> 2, Q3 = F0 >> 3;
    // stage all global coefficient tiles (coalesced, clamp at array end)
    for (int i = threadIdx.x; i < NQ3 + 8; i += 256) {
        int idx = Q3 + i; if (idx > L3 - 1) idx = L3 - 1;
        t3a[i] = pa3[idx];
        t3d[i] = sthr(pd3[idx], lam, alam);
    }
    for (int i = threadIdx.x; i < N2T + 1; i += 256) {
        int idx = A2 + i; if (idx > L2 - 1) idx = L2 - 1;
        t2[i] = sthr(pd2[idx], lam, alam);
    }
    for (int i = threadIdx.x; i < N1T; i += 256) {
        int idx = A1 + i; if (idx > L1 - 1) idx = L1 - 1;
        t1[i] = sthr(pd1[idx], lam, alam);
    }
    __syncthreads();
    // level 3 -> rec2
    for (int i = threadIdx.x; i < NQ3; i += 256) {
        float a0 = 0.f, a1v = 0.f;
#pragma unroll
        for (int p = 0; p < 8; ++p) {
            float a = t3a[i + p];
            float d = t3d[i + p];
            a0  = fmaf(a, DLO[2 * p + 1], a0);
            a0  = fmaf(d, DLO[14 - 2 * p], a0);
            a1v = fmaf(a, DLO[2 * p], a1v);
            a1v = fmaf(d, -DLO[15 - 2 * p], a1v);
        }
        r2[2 * i] = a0; r2[2 * i + 1] = a1v;
    }
    __syncthreads();
    // level 2 -> rec1
    for (int i = threadIdx.x; i < N1T / 2; i += 256) {
        float a0 = 0.f, a1v = 0.f;
#pragma unroll
        for (int p = 0; p < 8; ++p) {
            float a = r2[i + p];
            float d = t2[i + p];
            a0  = fmaf(a, DLO[2 * p + 1], a0);
            a0  = fmaf(d, DLO[14 - 2 * p], a0);
            a1v = fmaf(a, DLO[2 * p], a1v);
            a1v = fmaf(d, -DLO[15 - 2 * p], a1v);
        }
        r1[2 * i] = a0; r1[2 * i + 1] = a1v;
    }
    __syncthreads();
    // level 1 -> 4 outputs/thread-iter, float4 IO
    const float* orig = s ? res : trend;
    float* o_diff = out + (size_t)(2 * s) * L0;
    float* o_nn   = out + (size_t)(2 * s + 1) * L0;
    for (int i = threadIdx.x; i < NF0 / 4; i += 256) {
        int r0 = F0 + 4 * i;
        if (r0 >= L0) continue;
        float w[9], z[9];
#pragma unroll
        for (int p = 0; p < 9; ++p) { w[p] = r1[2 * i + p]; z[p] = t1[2 * i + p]; }
        float a0 = 0.f, a1v = 0.f, b0 = 0.f, b1 = 0.f;
#pragma unroll
        for (int p = 0; p < 8; ++p) {
            a0  = fmaf(w[p],     DLO[2 * p + 1], a0);
            a0  = fmaf(z[p],     DLO[14 - 2 * p], a0);
            a1v = fmaf(w[p],     DLO[2 * p], a1v);
            a1v = fmaf(z[p],    -DLO[15 - 2 * p], a1v);
            b0  = fmaf(w[p + 1], DLO[2 * p + 1], b0);
            b0  = fmaf(z[p + 1], DLO[14 - 2 * p], b0);
            b1  = fmaf(w[p + 1], DLO[2 * p], b1);
            b1  = fmaf(z[p + 1],-DLO[15 - 2 * p], b1);
        }
        float4 og = *(const float4*)(orig + r0);
        float4 nn; nn.x = a0; nn.y = a1v; nn.z = b0; nn.w = b1;
        float4 df; df.x = og.x - a0; df.y = og.y - a1v; df.z = og.z - b0; df.w = og.w - b1;
        *(float4*)(o_nn + r0)   = nn;
        *(float4*)(o_diff + r0) = df;
    }
}

extern "C" void kernel_launch(void* const* d_in, const int* in_sizes, int n_in,
                              void* d_out, int out_size, void* d_ws, size_t ws_size,
                              hipStream_t stream) {
    const float* x = (const float*)d_in[0];
    float* out = (float*)d_out;
    float* w = (float*)d_ws;

    float* trend = w;
    float* res   = trend + (size_t)L0;
    float* ca1   = res + (size_t)L0;
    float* cd1   = ca1 + 2 * (size_t)L1;
    float* cd2   = cd1 + 2 * (size_t)L1;
    float* ca3   = cd2 + 2 * (size_t)L2;
    float* cd3   = ca3 + 2 * (size_t)L3;
    unsigned* cand   = (unsigned*)(cd3 + 2 * (size_t)L3);
    unsigned* hist0  = cand + 2 * (size_t)L1;    // 16384 words (2048x2 bins, stride 4)
    unsigned* hist1  = hist0 + 16384;            // 8192 words
    unsigned* cnt    = hist1 + 8192;             // 2
    float*    lamArr = (float*)(cnt + 2);        // 2

    dim3 b256(256);

    init_kernel<<<64, b256, 0, stream>>>(hist0, hist1, cnt);
    {
        int nthreads = BB * (TT / TCH) * NNN;
        mavg_kernel<<<(nthreads + 255) / 256, b256, 0, stream>>>(x, trend, res);
    }
    dwt1_hist<<<GD1, b256, 0, stream>>>(trend, res, ca1, cd1, hist0);
    dwt23_compact<<<2 * GD23 + 2 * NCB, b256, 0, stream>>>(
        ca1, cd2, ca3, cd3, cd1, hist0, hist1, cand, cnt);
    select_final<<<2, 1024, 0, stream>>>(hist0, hist1, cand, cnt, lamArr);
    idwt_fused<<<dim3((L0 + NF0 - 1) / NF0, 2), b256, 0, stream>>>(
        ca3, cd3, cd2, cd1, trend, res, out, lamArr);
}